// Round 1
// baseline (672.388 us; speedup 1.0000x reference)
//
#include <hip/hip_runtime.h>
#include <math.h>

#define TBB 32
#define CC  256
#define NN  196
#define NJ  (TBB * NN)            // 6272
#define HD  1024
#define SLAB   ((size_t)TBB * CC * NN)   // 1,605,632
#define SLAB1K ((size_t)TBB * HD * NN)   // 6,422,528

struct Ptr6  { const float* p[6]; };
struct PtrM6 { float*       p[6]; };

// ---------------------------------------------------------------------------
// GEMM: Z[m, d, n] = sum_c W[d,c] * In[m, c, n]  (+ optional second pass with
// W2/In2 accumulated into the same accumulators, + optional bias/bias2)
// Columns flattened j = m*196 + n; NJ = 6272 = 98 * 64.
// 64x64 tile, 256 threads, 4x4 micro-tile, K-tile 16, single-buffered LDS.
// ---------------------------------------------------------------------------
__global__ __launch_bounds__(256) void gemm_tile(
    const float* __restrict__ W,  const float* __restrict__ In,
    const float* __restrict__ W2, const float* __restrict__ In2,
    const float* __restrict__ bias, const float* __restrict__ bias2,
    float* __restrict__ Z, int Cout, int Cin)
{
    __shared__ float As[16][64];
    __shared__ float Bs[16][64];
    const int t  = threadIdx.x;
    const int tx = t & 15, ty = t >> 4;
    const int d0 = blockIdx.x * 64;
    const int j0 = blockIdx.y * 64;

    float acc[4][4] = {{0.f}};

    // staging roles
    const int wrow = t >> 2;          // 0..63  (W row within tile)
    const int wk   = (t & 3) * 4;     // 0,4,8,12 (K offset, float4)
    const int skk  = t >> 4;          // 0..15  (In K-row)
    const int sj   = (t & 15) * 4;    // In col group

    size_t inoff[4];
    {
        int jb = j0 + sj;
        #pragma unroll
        for (int i = 0; i < 4; ++i) {
            int j = jb + i;
            int m = j / NN;
            int n = j - m * NN;
            inoff[i] = (size_t)m * Cin * NN + n;
        }
    }

    for (int pass = 0; pass < 2; ++pass) {
        const float* Wp = pass ? W2 : W;
        const float* Ip = pass ? In2 : In;
        if (Wp == nullptr) break;
        for (int k0 = 0; k0 < Cin; k0 += 16) {
            float4 w4 = *(const float4*)(Wp + (size_t)(d0 + wrow) * Cin + (k0 + wk));
            float bvals[4];
            #pragma unroll
            for (int i = 0; i < 4; ++i)
                bvals[i] = Ip[inoff[i] + (size_t)(k0 + skk) * NN];

            As[wk + 0][wrow] = w4.x;
            As[wk + 1][wrow] = w4.y;
            As[wk + 2][wrow] = w4.z;
            As[wk + 3][wrow] = w4.w;
            #pragma unroll
            for (int i = 0; i < 4; ++i) Bs[skk][sj + i] = bvals[i];
            __syncthreads();

            #pragma unroll
            for (int kk = 0; kk < 16; ++kk) {
                float4 a4 = *(const float4*)(&As[kk][ty * 4]);
                float4 b4 = *(const float4*)(&Bs[kk][tx * 4]);
                float ar[4] = {a4.x, a4.y, a4.z, a4.w};
                float br[4] = {b4.x, b4.y, b4.z, b4.w};
                #pragma unroll
                for (int i = 0; i < 4; ++i)
                    #pragma unroll
                    for (int jj = 0; jj < 4; ++jj)
                        acc[i][jj] = fmaf(ar[i], br[jj], acc[i][jj]);
            }
            __syncthreads();
        }
    }

    #pragma unroll
    for (int i = 0; i < 4; ++i) {
        int d = d0 + ty * 4 + i;
        float bv = 0.f;
        if (bias)  bv += bias[d];
        if (bias2) bv += bias2[d];
        #pragma unroll
        for (int jj = 0; jj < 4; ++jj) {
            int j = j0 + tx * 4 + jj;
            int m = j / NN;
            int n = j - m * NN;
            Z[(size_t)(m * Cout + d) * NN + n] = acc[i][jj] + bv;
        }
    }
}

// ---------------------------------------------------------------------------
// BN stats: per channel d, over (m, n). Double accumulation -> scale/shift so
// that norm = scale*z + shift, spike = (norm >= 1).
// grid (Cout, nconv)
// ---------------------------------------------------------------------------
__global__ __launch_bounds__(256) void bn_stats(
    Ptr6 Zs, Ptr6 gs, Ptr6 bs, int Cout,
    float* __restrict__ scale, float* __restrict__ shift)
{
    const int d = blockIdx.x, g = blockIdx.y, t = threadIdx.x;
    const float* Z = Zs.p[g];
    double s = 0.0, s2 = 0.0;
    for (int i = t; i < NJ; i += 256) {
        int m = i / NN, n = i - m * NN;
        double v = (double)Z[(size_t)(m * Cout + d) * NN + n];
        s += v; s2 += v * v;
    }
    __shared__ double sh[256], sh2[256];
    sh[t] = s; sh2[t] = s2;
    __syncthreads();
    for (int off = 128; off > 0; off >>= 1) {
        if (t < off) { sh[t] += sh[t + off]; sh2[t] += sh2[t + off]; }
        __syncthreads();
    }
    if (t == 0) {
        double mu  = sh[0] / (double)NJ;
        double var = sh2[0] / (double)NJ - mu * mu;
        double a   = (double)gs.p[g][d] / sqrt(var + 1e-5);
        scale[g * Cout + d] = (float)a;
        shift[g * Cout + d] = (float)((double)bs.p[g][d] - mu * a);
    }
}

// spike = (scale[d]*z + shift[d] >= 1)    grid (total/256, nconv)
__global__ __launch_bounds__(256) void bn_apply(
    Ptr6 Zs, PtrM6 Ss, const float* __restrict__ scale,
    const float* __restrict__ shift, int Cout, int total)
{
    int g = blockIdx.y;
    int idx = blockIdx.x * 256 + threadIdx.x;
    if (idx >= total) return;
    int d = (idx / NN) % Cout;
    float v = fmaf(scale[g * Cout + d], Zs.p[g][idx], shift[g * Cout + d]);
    Ss.p[g][idx] = (v >= 1.f) ? 1.f : 0.f;
}

// ---------------------------------------------------------------------------
// Attention for one (m, h): q,k,v are binary spikes in (m, c=h*16+dd, n)
// layout. attn = popcount(q&k)  [exact ints]; optional rpb-LIF; o-spike out.
// grid (32, 16), 256 threads (196 active in hot loops).
// ---------------------------------------------------------------------------
__global__ __launch_bounds__(256) void attention_k(
    const float* __restrict__ Q, const float* __restrict__ K,
    const float* __restrict__ V, const float* __restrict__ P,
    float* __restrict__ O)
{
    const int m = blockIdx.x;
    const int h = blockIdx.y;
    const int t = threadIdx.x;
    __shared__ unsigned int qb[196], kb[196], vb[196];
    __shared__ float Pl[841];

    if (P) { for (int i = t; i < 841; i += 256) Pl[i] = P[i]; }
    if (t < 196) {
        unsigned int q = 0, k = 0, v = 0;
        size_t base = (size_t)m * CC * NN + (size_t)h * 16 * NN + t;
        #pragma unroll
        for (int dd = 0; dd < 16; ++dd) {
            size_t off = base + (size_t)dd * NN;
            if (Q[off] > 0.5f) q |= (1u << dd);
            if (K[off] > 0.5f) k |= (1u << dd);
            if (V[off] > 0.5f) v |= (1u << dd);
        }
        qb[t] = q; kb[t] = k; vb[t] = v;
    }
    __syncthreads();

    if (t < 196) {
        int acc[16] = {0};
        const int ni = t / 14, nj = t - ni * 14;
        const unsigned int qr = qb[t];
        if (P) {
            for (int mm = 0; mm < 196; ++mm) {
                int a = __popc(qr & kb[mm]);
                int mi = mm / 14, mj = mm - mi * 14;
                float sv = (float)a + Pl[(ni - mi + 14) * 29 + (nj - mj + 14)];
                if (sv >= 1.f) {
                    unsigned int vv = vb[mm];
                    #pragma unroll
                    for (int dd = 0; dd < 16; ++dd)
                        acc[dd] += (vv >> dd) & 1;
                }
            }
        } else {
            for (int mm = 0; mm < 196; ++mm) {
                int a = __popc(qr & kb[mm]);
                if (a) {
                    unsigned int vv = vb[mm];
                    #pragma unroll
                    for (int dd = 0; dd < 16; ++dd)
                        acc[dd] += ((vv >> dd) & 1) ? a : 0;
                }
            }
        }
        size_t base = (size_t)m * CC * NN + (size_t)h * 16 * NN + t;
        #pragma unroll
        for (int dd = 0; dd < 16; ++dd)
            O[base + (size_t)dd * NN] = (acc[dd] >= 2) ? 1.f : 0.f;  // 0.25*acc >= 0.5
    }
}

// x1 = x + sx ; y1 = y + sy
__global__ __launch_bounds__(256) void add_residual2(
    const float* __restrict__ x, const float* __restrict__ y,
    const float* __restrict__ sx, const float* __restrict__ sy,
    float* __restrict__ X1, float* __restrict__ Y1)
{
    size_t i = (size_t)blockIdx.x * 256 + threadIdx.x;
    if (i >= SLAB) return;
    X1[i] = x[i] + sx[i];
    Y1[i] = y[i] + sy[i];
}

// spike = (z >= 1)
__global__ __launch_bounds__(256) void lif1(
    const float* __restrict__ Z, float* __restrict__ S, int total)
{
    int i = blockIdx.x * 256 + threadIdx.x;
    if (i >= total) return;
    S[i] = (Z[i] >= 1.f) ? 1.f : 0.f;
}

// out = cur + o
__global__ __launch_bounds__(256) void final_add(
    const float* __restrict__ cur, const float* __restrict__ o,
    float* __restrict__ out, int total)
{
    int i = blockIdx.x * 256 + threadIdx.x;
    if (i >= total) return;
    out[i] = cur[i] + o[i];
}

extern "C" void kernel_launch(void* const* d_in, const int* in_sizes, int n_in,
                              void* d_out, int out_size, void* d_ws, size_t ws_size,
                              hipStream_t stream)
{
    const float* x     = (const float*)d_in[0];
    const float* y     = (const float*)d_in[1];
    const float* av_w  = (const float*)d_in[2];
    const float* av_g  = (const float*)d_in[3];
    const float* av_b  = (const float*)d_in[4];
    const float* va_w  = (const float*)d_in[5];
    const float* va_g  = (const float*)d_in[6];
    const float* va_b  = (const float*)d_in[7];
    const float* P_rpb = (const float*)d_in[8];
    const float* fc1_w = (const float*)d_in[9];
    const float* fc1_b = (const float*)d_in[10];
    const float* fc2_w = (const float*)d_in[11];
    const float* fc2_b = (const float*)d_in[12];
    const float* m1_w  = (const float*)d_in[13];
    const float* m1_b  = (const float*)d_in[14];
    const float* m1_g  = (const float*)d_in[15];
    const float* m1_bb = (const float*)d_in[16];
    const float* m2_w  = (const float*)d_in[17];
    const float* m2_b  = (const float*)d_in[18];
    const float* m2_g  = (const float*)d_in[19];
    const float* m2_bb = (const float*)d_in[20];
    float* out = (float*)d_out;

    float* ws    = (float*)d_ws;
    float* A     = ws;               // 6 * SLAB (z / spikes, later x1,y1, later m1 z / h)
    float* Bf    = A  + 6 * SLAB;    // 2 * SLAB (o-spikes; later fc z + cur)
    float* Cf    = Bf + 2 * SLAB;    // 2 * SLAB (W3 z / s_x,s_y; later m2 z / o)
    float* scale = Cf + 2 * SLAB;    // 6 * 1024
    float* shift = scale + 6 * 1024;

    const size_t CC2 = (size_t)CC * CC;
    const int blocksSlab  = (int)(SLAB / 256);     // 6272
    const int blocksSlab1 = (int)(SLAB1K / 256);   // 25088

    // ---- Stage A: 6 first-layer convs -> A slabs ------------------------
    const float* Wl[6] = { av_w, av_w + CC2, av_w + 2*CC2, va_w, va_w + CC2, va_w + 2*CC2 };
    const float* Il[6] = { x, y, y, y, x, x };
    for (int i = 0; i < 6; ++i)
        gemm_tile<<<dim3(CC/64, NJ/64), 256, 0, stream>>>(
            Wl[i], Il[i], nullptr, nullptr, nullptr, nullptr, A + i*SLAB, CC, CC);

    Ptr6 Zs{}, gs{}, bs{}; PtrM6 Ss{};
    const float* gl[6] = { av_g, av_g + CC, av_g + 2*CC, va_g, va_g + CC, va_g + 2*CC };
    const float* bl[6] = { av_b, av_b + CC, av_b + 2*CC, va_b, va_b + CC, va_b + 2*CC };
    for (int i = 0; i < 6; ++i) {
        Zs.p[i] = A + i*SLAB; Ss.p[i] = A + i*SLAB; gs.p[i] = gl[i]; bs.p[i] = bl[i];
    }
    bn_stats<<<dim3(CC, 6), 256, 0, stream>>>(Zs, gs, bs, CC, scale, shift);
    bn_apply<<<dim3(blocksSlab, 6), 256, 0, stream>>>(Zs, Ss, scale, shift, CC, (int)SLAB);

    // ---- Stage B: attention (exact, bit-packed) -------------------------
    attention_k<<<dim3(TBB, 16), 256, 0, stream>>>(A, A + SLAB, A + 2*SLAB, nullptr, Bf);
    attention_k<<<dim3(TBB, 16), 256, 0, stream>>>(A + 3*SLAB, A + 4*SLAB, A + 5*SLAB, P_rpb, Bf + SLAB);

    // ---- Stage C: W3 conv + BN + LIF -> s_x, s_y in Cf ------------------
    gemm_tile<<<dim3(CC/64, NJ/64), 256, 0, stream>>>(
        av_w + 3*CC2, Bf, nullptr, nullptr, nullptr, nullptr, Cf, CC, CC);
    gemm_tile<<<dim3(CC/64, NJ/64), 256, 0, stream>>>(
        va_w + 3*CC2, Bf + SLAB, nullptr, nullptr, nullptr, nullptr, Cf + SLAB, CC, CC);
    Zs.p[0] = Cf; Zs.p[1] = Cf + SLAB; Ss.p[0] = Cf; Ss.p[1] = Cf + SLAB;
    gs.p[0] = av_g + 3*CC; gs.p[1] = va_g + 3*CC;
    bs.p[0] = av_b + 3*CC; bs.p[1] = va_b + 3*CC;
    bn_stats<<<dim3(CC, 2), 256, 0, stream>>>(Zs, gs, bs, CC, scale, shift);
    bn_apply<<<dim3(blocksSlab, 2), 256, 0, stream>>>(Zs, Ss, scale, shift, CC, (int)SLAB);

    // ---- x1 = x + s_x ; y1 = y + s_y  (into A slots 0,1) ---------------
    add_residual2<<<blocksSlab, 256, 0, stream>>>(x, y, Cf, Cf + SLAB, A, A + SLAB);

    // ---- fc1@x1 + fc2@y1 + biases -> Bf ; cur = (z>=1) -> Bf+SLAB ------
    gemm_tile<<<dim3(CC/64, NJ/64), 256, 0, stream>>>(
        fc1_w, A, fc2_w, A + SLAB, fc1_b, fc2_b, Bf, CC, CC);
    lif1<<<blocksSlab, 256, 0, stream>>>(Bf, Bf + SLAB, (int)SLAB);

    // ---- m1: (1024x256) @ cur + BN + LIF -> h in A ---------------------
    gemm_tile<<<dim3(HD/64, NJ/64), 256, 0, stream>>>(
        m1_w, Bf + SLAB, nullptr, nullptr, m1_b, nullptr, A, HD, CC);
    Zs.p[0] = A; Ss.p[0] = A; gs.p[0] = m1_g; bs.p[0] = m1_bb;
    bn_stats<<<dim3(HD, 1), 256, 0, stream>>>(Zs, gs, bs, HD, scale, shift);
    bn_apply<<<dim3(blocksSlab1, 1), 256, 0, stream>>>(Zs, Ss, scale, shift, HD, (int)SLAB1K);

    // ---- m2: (256x1024) @ h + BN + LIF -> o in Cf ----------------------
    gemm_tile<<<dim3(CC/64, NJ/64), 256, 0, stream>>>(
        m2_w, A, nullptr, nullptr, m2_b, nullptr, Cf, CC, HD);
    Zs.p[0] = Cf; Ss.p[0] = Cf; gs.p[0] = m2_g; bs.p[0] = m2_bb;
    bn_stats<<<dim3(CC, 1), 256, 0, stream>>>(Zs, gs, bs, CC, scale, shift);
    bn_apply<<<dim3(blocksSlab, 1), 256, 0, stream>>>(Zs, Ss, scale, shift, CC, (int)SLAB);

    // ---- out = cur + o --------------------------------------------------
    final_add<<<blocksSlab, 256, 0, stream>>>(Bf + SLAB, Cf, out, (int)SLAB);
}